// Round 9
// baseline (20.296 us; speedup 1.0000x reference)
//
#include <hip/hip_runtime.h>
#include <math.h>

#define EPS 1e-8f
#define NPTS 24
#define MAXN_LDS 2048      // row kernel supports n <= 2048
#define CHUNK 512          // boxes staged per chunk (14KB raw)
#define NREG 64            // fallback pipeline worklist regions
#define CTR_STRIDE 64

// ---- constexpr Batcher odd-even mergesort comparator network for NPTS=24 ----
struct Net {
    int n;
    unsigned char lo[256];
    unsigned char hi[256];
};
constexpr Net build_net() {
    Net net{};
    net.n = 0;
    for (int p = 1; p < NPTS; p <<= 1)
        for (int k = p; k >= 1; k >>= 1)
            for (int j = k % p; j + k < NPTS; j += 2 * k)
                for (int i = 0; i < k && i + j + k < NPTS; ++i)
                    if ((i + j) / (2 * p) == (i + j + k) / (2 * p)) {
                        net.lo[net.n] = (unsigned char)(i + j);
                        net.hi[net.n] = (unsigned char)(i + j + k);
                        ++net.n;
                    }
    return net;
}
constexpr Net NET = build_net();

// ---- verified heavy path: full sort of (key, px, py) ----
// Measured live set = 88 VGPRs (R7). Needs the >=128-VGPR budget provided by
// row_kernel's waves_per_eu(4,4) pin (default 8-wave target allocates 64 and
// spills the sort to scratch -- R5 measured).
__device__ __forceinline__ float pair_area(const float* __restrict__ A,
                                           const float* __restrict__ B)
{
    float ax = A[0], ay = A[1], adx = A[3], ady = A[4], ayaw = A[6];
    float bx = B[0], by = B[1], bdx = B[3], bdy = B[4], byaw = B[6];

    float ca = __builtin_cosf(ayaw), sa = __builtin_sinf(ayaw);
    float cb = __builtin_cosf(byaw), sb = __builtin_sinf(byaw);

    const float tx[4] = {0.5f, 0.5f, -0.5f, -0.5f};
    const float ty[4] = {0.5f, -0.5f, -0.5f, 0.5f};

    float cax[4], cay[4], cbx[4], cby[4];
#pragma unroll
    for (int k = 0; k < 4; ++k) {
        float lx = tx[k] * adx, ly = ty[k] * ady;
        cax[k] = lx * ca - ly * sa + ax;
        cay[k] = lx * sa + ly * ca + ay;
        lx = tx[k] * bdx; ly = ty[k] * bdy;
        cbx[k] = lx * cb - ly * sb + bx;
        cby[k] = lx * sb + ly * cb + by;
    }

    float px[NPTS], py[NPTS];
    bool valid[NPTS];

#pragma unroll
    for (int k = 0; k < 4; ++k) {
        float relx = cax[k] - bx, rely = cay[k] - by;
        float rx = relx * cb + rely * sb;
        float ry = -relx * sb + rely * cb;
        valid[k] = (fabsf(rx) <= bdx * 0.5f + 1e-5f) &&
                   (fabsf(ry) <= bdy * 0.5f + 1e-5f);
        px[k] = cax[k]; py[k] = cay[k];
    }
#pragma unroll
    for (int k = 0; k < 4; ++k) {
        float relx = cbx[k] - ax, rely = cby[k] - ay;
        float rx = relx * ca + rely * sa;
        float ry = -relx * sa + rely * ca;
        valid[4 + k] = (fabsf(rx) <= adx * 0.5f + 1e-5f) &&
                       (fabsf(ry) <= ady * 0.5f + 1e-5f);
        px[4 + k] = cbx[k]; py[4 + k] = cby[k];
    }

#pragma unroll
    for (int a = 0; a < 4; ++a) {
        int a2 = (a + 1) & 3;
        float p1x = cax[a], p1y = cay[a];
        float d1x = cax[a2] - p1x, d1y = cay[a2] - p1y;
#pragma unroll
        for (int b = 0; b < 4; ++b) {
            int b2 = (b + 1) & 3;
            float q1x = cbx[b], q1y = cby[b];
            float d2x = cbx[b2] - q1x, d2y = cby[b2] - q1y;
            float denom = d1x * d2y - d1y * d2x;
            bool dok = fabsf(denom) > EPS;
            float safe = dok ? denom : 1.0f;
            float inv = __builtin_amdgcn_rcpf(safe);
            float dqx = q1x - p1x, dqy = q1y - p1y;
            float t = (dqx * d2y - dqy * d2x) * inv;
            float u = (dqx * d1y - dqy * d1x) * inv;
            bool v = dok && (t >= 0.0f) && (t <= 1.0f) && (u >= 0.0f) && (u <= 1.0f);
            int o = 8 + a * 4 + b;
            px[o] = p1x + t * d1x;
            py[o] = p1y + t * d1y;
            valid[o] = v;
        }
    }

    int cnt = 0;
    float sx = 0.0f, sy = 0.0f;
#pragma unroll
    for (int k = 0; k < NPTS; ++k) {
        if (valid[k]) cnt++;
        float w = valid[k] ? 1.0f : 0.0f;
        sx += px[k] * w;
        sy += py[k] * w;
    }
    float cntf = (float)(cnt > 1 ? cnt : 1);
    float cx_ = sx / cntf, cy_ = sy / cntf;

    unsigned key[NPTS];
#pragma unroll
    for (int k = 0; k < NPTS; ++k) {
        float rx = px[k] - cx_, ry = py[k] - cy_;
        float axx = fabsf(rx), ayy = fabsf(ry);
        float d = fmaxf(axx + ayy, 1e-30f);
        float r = ry * __builtin_amdgcn_rcpf(d);
        float t = (rx >= 0.0f) ? r : ((ry >= 0.0f) ? 2.0f - r : -2.0f - r);
        unsigned u = __float_as_uint(t);
        unsigned ordered = u ^ ((unsigned)((int)u >> 31) | 0x80000000u);
        key[k] = valid[k] ? ((ordered & 0xFFFFFFE0u) | (unsigned)k)
                          : (0xFFFFFF00u | (unsigned)k);
    }

#pragma unroll
    for (int c = 0; c < NET.n; ++c) {
        int lo = NET.lo[c], hi = NET.hi[c];
        bool sw = key[hi] < key[lo];
        unsigned kl = key[lo], kh = key[hi];
        float xl = px[lo], xh = px[hi];
        float yl = py[lo], yh = py[hi];
        key[lo] = sw ? kh : kl;  key[hi] = sw ? kl : kh;
        px[lo]  = sw ? xh : xl;  px[hi]  = sw ? xl : xh;
        py[lo]  = sw ? yh : yl;  py[hi]  = sw ? yl : yh;
    }

    float lastx = 0.0f, lasty = 0.0f;
#pragma unroll
    for (int r = 0; r < NPTS; ++r) {
        bool isLast = (r == cnt - 1);
        lastx = isLast ? px[r] : lastx;
        lasty = isLast ? py[r] : lasty;
    }

    float s = 0.0f;
#pragma unroll
    for (int r = 0; r + 1 < NPTS; ++r) {
        float cr = px[r] * py[r + 1] - px[r + 1] * py[r];
        s += (r + 1 < cnt) ? cr : 0.0f;
    }
    s += (cnt >= 1) ? (lastx * py[0] - px[0] * lasty) : 0.0f;

    float area = 0.5f * fabsf(s);
    return (cnt >= 3) ? area : 0.0f;
}

// ============================================================================
// Row kernel R9 — R8 with the staging/cull restructured (single lever):
// R8's SoA staging issued 32 stride-28B scalar gathers/thread: each wave-
// instruction touches 28 cache lines and the 4 field-loads re-touch the same
// lines 4x -> ~14.3k TA transactions/CU ~ 6.8us (the R3/R8 shared cost).
// R9: stage 512-box chunks (14KB) RAW via coalesced float4 (each line touched
// once, ~900/block), then cull ONE BOX PER LANE from the raw chunk:
//   LDS addr stride = 7 words, gcd(7,32)=1 -> 2 lanes/bank = conflict-free
//   (R7's 756K conflicts came from 4-box/lane stride-28-word reads).
// Zero-stores are per-lane contiguous -> hardware-coalesced.
// LDS 18.4KB -> 4 blocks/CU at waves_per_eu(4,4) (128-VGPR budget, no spill:
// heavy path needs 88 regs measured).
// ============================================================================
__global__ __launch_bounds__(256)
__attribute__((amdgpu_waves_per_eu(4, 4)))
void row_kernel(
    const float* __restrict__ boxes, float* __restrict__ out, int m, int n)
{
    __shared__ __align__(16) float chunk[CHUNK * 7];   // 14KB raw box chunk
    __shared__ unsigned short wl[MAXN_LDS];
    __shared__ unsigned lcnt;

    const int i    = blockIdx.x;
    const int tid  = threadIdx.x;
    const int wv   = tid >> 6;
    const int lane = tid & 63;

    if (tid == 0) lcnt = 0;

    // ---- i-box (broadcast loads) ----
    const float* bi = boxes + (size_t)i * 7;
    float xi = bi[0], yi = bi[1];
    float dxi = bi[3], dyi = bi[4];
    float ri = 0.5f * sqrtf(dxi * dxi + dyi * dyi) + 0.005f;

    const unsigned long long below = (1ull << lane) - 1ull;
    float* orow = out + (size_t)i * n;

    // ---- chunked stage + cull ----
    for (int c0 = 0; c0 < n; c0 += CHUNK) {
        int cb = n - c0; if (cb > CHUNK) cb = CHUNK;
        int words = cb * 7;
        const float* src = boxes + (size_t)(m + c0) * 7;

        // coalesced raw copy (float4 bulk + scalar tail); each line once
        if ((((size_t)src) & 15) == 0) {
            int n4 = words >> 2;
            const float4* s4 = (const float4*)src;
            float4* d4 = (float4*)chunk;
            for (int t = tid; t < n4; t += 256) d4[t] = s4[t];
            for (int t = (n4 << 2) + tid; t < words; t += 256)
                chunk[t] = src[t];
        } else {
            for (int t = tid; t < words; t += 256) chunk[t] = src[t];
        }
        __syncthreads();   // chunk ready (also orders lcnt=0 on 1st iter)

        // cull: one box per lane; stride-7-word LDS reads = 2-way, free
#pragma unroll
        for (int half = 0; half < CHUNK / 256; ++half) {
            int tt = half * 256 + tid;            // box index within chunk
            int j  = c0 + tt;
            bool keep = false;
            if (tt < cb) {
                const float* bj = &chunk[tt * 7];
                float xj = bj[0], yj = bj[1];
                float dxj = bj[3], dyj = bj[4];
                float rj = 0.5f * sqrtf(dxj * dxj + dyj * dyj) + 0.005f;
                float ddx = xi - xj, ddy = yi - yj, rr = ri + rj;
                keep = (ddx * ddx + ddy * ddy) <= rr * rr;
                if (!keep) orow[j] = 0.0f;        // contiguous per wave
            }
            unsigned long long mask = __ballot(keep);
            int c = __popcll(mask);
            if (c > 0) {
                int lead = __ffsll(mask) - 1;
                unsigned base = 0;
                if (lane == lead) base = atomicAdd(&lcnt, (unsigned)c);
                base = (unsigned)__shfl((int)base, lead, 64);
                if (keep) {
                    int rank = __popcll(mask & below);
                    wl[base + rank] = (unsigned short)j;
                }
            }
        }
        __syncthreads();   // chunk consumed; safe to overwrite next iter
    }

    // ---- process survivors; round r handled by wave (i+r)&3 ----
    unsigned cnt = lcnt;
    unsigned r = 0;
    for (unsigned base = 0; base < cnt; base += 64, ++r) {
        if ((int)((i + r) & 3u) == wv) {
            unsigned t = base + (unsigned)lane;
            if (t < cnt) {
                int j = (int)wl[t];
                orow[j] = pair_area(bi, boxes + (size_t)(m + j) * 7);
            }
        }
    }
}

// ============================================================================
// Fallback pipeline — unchanged (only for odd shapes).
// ============================================================================
__global__ __launch_bounds__(256) void prep_kernel(
    const float* __restrict__ boxes, float* __restrict__ xs,
    float* __restrict__ ys, float* __restrict__ rs,
    unsigned* __restrict__ counters, int total)
{
    int t = blockIdx.x * blockDim.x + threadIdx.x;
    if (t < NREG * CTR_STRIDE) counters[t] = 0;
    if (t < total) {
        float dx = boxes[(size_t)t * 7 + 3];
        float dy = boxes[(size_t)t * 7 + 4];
        xs[t] = boxes[(size_t)t * 7 + 0];
        ys[t] = boxes[(size_t)t * 7 + 1];
        rs[t] = 0.5f * sqrtf(dx * dx + dy * dy) + 0.005f;
    }
}

__global__ __launch_bounds__(256) void cull_kernel(
    const float* __restrict__ xs, const float* __restrict__ ys,
    const float* __restrict__ rs, float* __restrict__ out,
    unsigned* __restrict__ counters, unsigned* __restrict__ regions,
    int m, int n, unsigned reg_cap)
{
    int jb = blockIdx.x, i = blockIdx.y;
    int tid = threadIdx.x;
    int j = jb * 256 + tid;

    bool keep = false;
    if (j < n) {
        float dx = xs[i] - xs[m + j];
        float dy = ys[i] - ys[m + j];
        float rr = rs[i] + rs[m + j];
        keep = (dx * dx + dy * dy) <= rr * rr;
        out[(size_t)i * n + j] = 0.0f;
    }

    unsigned long long mask = __ballot(keep);
    if (mask == 0ull) return;

    int lane = tid & 63;
    unsigned gwid = ((unsigned)(i * gridDim.x + jb) << 2) | ((unsigned)tid >> 6);
    unsigned region = gwid & (NREG - 1);

    int c = __popcll(mask);
    int lead = __ffsll((unsigned long long)mask) - 1;
    unsigned pos = 0;
    if (lane == lead) pos = atomicAdd(&counters[region * CTR_STRIDE], (unsigned)c);
    pos = (unsigned)__shfl((int)pos, lead, 64);
    if (keep) {
        int rank = __popcll(mask & ((1ull << lane) - 1ull));
        regions[(size_t)region * reg_cap + pos + rank] =
            ((unsigned)i << 12) | (unsigned)j;
    }
}

__global__ __launch_bounds__(64) void process_kernel(
    const float* __restrict__ boxes, float* __restrict__ out,
    const unsigned* __restrict__ counters, const unsigned* __restrict__ regions,
    int m, int n, unsigned reg_cap)
{
    unsigned region = blockIdx.x >> 2;
    unsigned cnt = counters[region * CTR_STRIDE];
    const unsigned* seg = regions + (size_t)region * reg_cap;
    for (unsigned t = ((blockIdx.x & 3u) << 6) | threadIdx.x; t < cnt; t += 256) {
        unsigned v = seg[t];
        int i = (int)(v >> 12);
        int j = (int)(v & 4095u);
        const float* A = boxes + (size_t)i * 7;
        const float* B = boxes + (size_t)(m + j) * 7;
        out[(size_t)i * n + j] = pair_area(A, B);
    }
}

__global__ __launch_bounds__(256) void overlap_kernel(
    const float* __restrict__ boxes, float* __restrict__ out, int m, int n)
{
    int j = blockIdx.x * blockDim.x + threadIdx.x;
    int i = blockIdx.y;
    if (j >= n) return;
    const float* A = boxes + (size_t)i * 7;
    const float* B = boxes + (size_t)(m + j) * 7;
    out[(size_t)i * n + j] = pair_area(A, B);
}

extern "C" void kernel_launch(void* const* d_in, const int* in_sizes, int n_in,
                              void* d_out, int out_size, void* d_ws, size_t ws_size,
                              hipStream_t stream) {
    const float* boxes = (const float*)d_in[0];
    float* out = (float*)d_out;
    int total = in_sizes[0] / 7;   // 3000 boxes
    int m = total / 3;             // 1000
    int n = total - m;             // 2000

    // ---------------- single-dispatch row kernel ----------------
    if (n > 0 && n <= MAXN_LDS && (n % 4) == 0 && m >= 1) {
        hipLaunchKernelGGL(row_kernel, dim3((unsigned)m), dim3(256), 0, stream,
                           boxes, out, m, n);
        return;
    }

    // ---------------- fallback: verified 3-kernel pipeline ----------------
    int bpr = (n + 255) / 256;
    unsigned total_waves = (unsigned)(bpr * m) * 4u;
    unsigned reg_cap = ((total_waves + NREG - 1) / NREG) * 64u;

    size_t ctr_off = 0;
    size_t xs_off  = ctr_off + (size_t)NREG * CTR_STRIDE * 4;
    size_t ys_off  = xs_off + (size_t)total * 4;
    size_t rs_off  = ys_off + (size_t)total * 4;
    size_t reg_off = ((rs_off + (size_t)total * 4) + 255) & ~(size_t)255;
    size_t need    = reg_off + (size_t)NREG * reg_cap * 4;

    if (ws_size < need || n > 4095) {
        dim3 block(256, 1, 1);
        dim3 grid((n + 255) / 256, m, 1);
        hipLaunchKernelGGL(overlap_kernel, grid, block, 0, stream, boxes, out, m, n);
        return;
    }

    unsigned* counters = (unsigned*)((char*)d_ws + ctr_off);
    float* xs = (float*)((char*)d_ws + xs_off);
    float* ys = (float*)((char*)d_ws + ys_off);
    float* rs = (float*)((char*)d_ws + rs_off);
    unsigned* regions = (unsigned*)((char*)d_ws + reg_off);

    int prep_threads = (NREG * CTR_STRIDE > total) ? NREG * CTR_STRIDE : total;
    hipLaunchKernelGGL(prep_kernel, dim3((prep_threads + 255) / 256), dim3(256),
                       0, stream, boxes, xs, ys, rs, counters, total);

    hipLaunchKernelGGL(cull_kernel, dim3(bpr, m, 1), dim3(256), 0, stream,
                       xs, ys, rs, out, counters, regions, m, n, reg_cap);

    hipLaunchKernelGGL(process_kernel, dim3(NREG * 4, 1, 1), dim3(64), 0, stream,
                       boxes, out, counters, regions, m, n, reg_cap);
}

// Round 10
// 16.997 us; speedup vs baseline: 1.1941x; 1.1941x over previous
//
#include <hip/hip_runtime.h>
#include <math.h>

#define EPS 1e-8f
#define NPTS 24
#define MAXN_LDS 2048      // row kernel supports n <= 2048
#define CHUNKB 1024        // boxes staged per chunk (28KB raw)
#define ROWS 2             // rows per block
#define NREG 64            // fallback pipeline worklist regions
#define CTR_STRIDE 64

// ---- constexpr Batcher odd-even mergesort comparator network for NPTS=24 ----
struct Net {
    int n;
    unsigned char lo[256];
    unsigned char hi[256];
};
constexpr Net build_net() {
    Net net{};
    net.n = 0;
    for (int p = 1; p < NPTS; p <<= 1)
        for (int k = p; k >= 1; k >>= 1)
            for (int j = k % p; j + k < NPTS; j += 2 * k)
                for (int i = 0; i < k && i + j + k < NPTS; ++i)
                    if ((i + j) / (2 * p) == (i + j + k) / (2 * p)) {
                        net.lo[net.n] = (unsigned char)(i + j);
                        net.hi[net.n] = (unsigned char)(i + j + k);
                        ++net.n;
                    }
    return net;
}
constexpr Net NET = build_net();

// ---- verified heavy path: full sort of (key, px, py) ----
// Measured live set = 88 VGPRs (R7). Needs the >=128-VGPR budget provided by
// row_kernel's waves_per_eu(4,4) pin (default 8-wave target allocates 64 and
// spills the sort to scratch -- R5 measured).
__device__ __forceinline__ float pair_area(const float* __restrict__ A,
                                           const float* __restrict__ B)
{
    float ax = A[0], ay = A[1], adx = A[3], ady = A[4], ayaw = A[6];
    float bx = B[0], by = B[1], bdx = B[3], bdy = B[4], byaw = B[6];

    float ca = __builtin_cosf(ayaw), sa = __builtin_sinf(ayaw);
    float cb = __builtin_cosf(byaw), sb = __builtin_sinf(byaw);

    const float tx[4] = {0.5f, 0.5f, -0.5f, -0.5f};
    const float ty[4] = {0.5f, -0.5f, -0.5f, 0.5f};

    float cax[4], cay[4], cbx[4], cby[4];
#pragma unroll
    for (int k = 0; k < 4; ++k) {
        float lx = tx[k] * adx, ly = ty[k] * ady;
        cax[k] = lx * ca - ly * sa + ax;
        cay[k] = lx * sa + ly * ca + ay;
        lx = tx[k] * bdx; ly = ty[k] * bdy;
        cbx[k] = lx * cb - ly * sb + bx;
        cby[k] = lx * sb + ly * cb + by;
    }

    float px[NPTS], py[NPTS];
    bool valid[NPTS];

#pragma unroll
    for (int k = 0; k < 4; ++k) {
        float relx = cax[k] - bx, rely = cay[k] - by;
        float rx = relx * cb + rely * sb;
        float ry = -relx * sb + rely * cb;
        valid[k] = (fabsf(rx) <= bdx * 0.5f + 1e-5f) &&
                   (fabsf(ry) <= bdy * 0.5f + 1e-5f);
        px[k] = cax[k]; py[k] = cay[k];
    }
#pragma unroll
    for (int k = 0; k < 4; ++k) {
        float relx = cbx[k] - ax, rely = cby[k] - ay;
        float rx = relx * ca + rely * sa;
        float ry = -relx * sa + rely * ca;
        valid[4 + k] = (fabsf(rx) <= adx * 0.5f + 1e-5f) &&
                       (fabsf(ry) <= ady * 0.5f + 1e-5f);
        px[4 + k] = cbx[k]; py[4 + k] = cby[k];
    }

#pragma unroll
    for (int a = 0; a < 4; ++a) {
        int a2 = (a + 1) & 3;
        float p1x = cax[a], p1y = cay[a];
        float d1x = cax[a2] - p1x, d1y = cay[a2] - p1y;
#pragma unroll
        for (int b = 0; b < 4; ++b) {
            int b2 = (b + 1) & 3;
            float q1x = cbx[b], q1y = cby[b];
            float d2x = cbx[b2] - q1x, d2y = cby[b2] - q1y;
            float denom = d1x * d2y - d1y * d2x;
            bool dok = fabsf(denom) > EPS;
            float safe = dok ? denom : 1.0f;
            float inv = __builtin_amdgcn_rcpf(safe);
            float dqx = q1x - p1x, dqy = q1y - p1y;
            float t = (dqx * d2y - dqy * d2x) * inv;
            float u = (dqx * d1y - dqy * d1x) * inv;
            bool v = dok && (t >= 0.0f) && (t <= 1.0f) && (u >= 0.0f) && (u <= 1.0f);
            int o = 8 + a * 4 + b;
            px[o] = p1x + t * d1x;
            py[o] = p1y + t * d1y;
            valid[o] = v;
        }
    }

    int cnt = 0;
    float sx = 0.0f, sy = 0.0f;
#pragma unroll
    for (int k = 0; k < NPTS; ++k) {
        if (valid[k]) cnt++;
        float w = valid[k] ? 1.0f : 0.0f;
        sx += px[k] * w;
        sy += py[k] * w;
    }
    float cntf = (float)(cnt > 1 ? cnt : 1);
    float cx_ = sx / cntf, cy_ = sy / cntf;

    unsigned key[NPTS];
#pragma unroll
    for (int k = 0; k < NPTS; ++k) {
        float rx = px[k] - cx_, ry = py[k] - cy_;
        float axx = fabsf(rx), ayy = fabsf(ry);
        float d = fmaxf(axx + ayy, 1e-30f);
        float r = ry * __builtin_amdgcn_rcpf(d);
        float t = (rx >= 0.0f) ? r : ((ry >= 0.0f) ? 2.0f - r : -2.0f - r);
        unsigned u = __float_as_uint(t);
        unsigned ordered = u ^ ((unsigned)((int)u >> 31) | 0x80000000u);
        key[k] = valid[k] ? ((ordered & 0xFFFFFFE0u) | (unsigned)k)
                          : (0xFFFFFF00u | (unsigned)k);
    }

#pragma unroll
    for (int c = 0; c < NET.n; ++c) {
        int lo = NET.lo[c], hi = NET.hi[c];
        bool sw = key[hi] < key[lo];
        unsigned kl = key[lo], kh = key[hi];
        float xl = px[lo], xh = px[hi];
        float yl = py[lo], yh = py[hi];
        key[lo] = sw ? kh : kl;  key[hi] = sw ? kl : kh;
        px[lo]  = sw ? xh : xl;  px[hi]  = sw ? xl : xh;
        py[lo]  = sw ? yh : yl;  py[hi]  = sw ? yl : yh;
    }

    float lastx = 0.0f, lasty = 0.0f;
#pragma unroll
    for (int r = 0; r < NPTS; ++r) {
        bool isLast = (r == cnt - 1);
        lastx = isLast ? px[r] : lastx;
        lasty = isLast ? py[r] : lasty;
    }

    float s = 0.0f;
#pragma unroll
    for (int r = 0; r + 1 < NPTS; ++r) {
        float cr = px[r] * py[r + 1] - px[r + 1] * py[r];
        s += (r + 1 < cnt) ? cr : 0.0f;
    }
    s += (cnt >= 1) ? (lastx * py[0] - px[0] * lasty) : 0.0f;

    float area = 0.5f * fabsf(s);
    return (cnt >= 3) ? area : 0.0f;
}

// ============================================================================
// Row-pair kernel R10 — amortize per-block work across ROWS=2 rows:
// R3/R8/R9 plateau at 19-20us across different staging/spill/occupancy
// configs => per-block fixed work (stage 56KB + barriers + cull reads) x1000
// blocks dominates the kernel. This block processes TWO rows:
//   - grid 500 x 512 threads (8 waves); 2 blocks/CU x 8 = 16 waves/CU =
//     exactly the waves_per_eu(4,4) pin (128-VGPR budget, 88 needed, no spill)
//   - chunk of 1024 boxes (28KB) staged coalesced ONCE, tested against BOTH
//     rows (LDS read amortized 2x; device staged bytes 56->28MB)
//   - survivors packed (row<<12|j) into ONE worklist: phase-2 lane
//     utilization doubles (~12 -> ~24 active lanes per wave-round)
//   - LDS 36.5KB x 2 blocks = 73KB < 160KB
// ============================================================================
__global__ __launch_bounds__(512)
__attribute__((amdgpu_waves_per_eu(4, 4)))
void rowpair_kernel(
    const float* __restrict__ boxes, float* __restrict__ out, int m, int n)
{
    __shared__ __align__(16) float chunk[CHUNKB * 7];      // 28KB raw boxes
    __shared__ unsigned short wl[ROWS * MAXN_LDS];         // packed (rl<<12|j)
    __shared__ unsigned lcnt;

    const int i0   = blockIdx.x * ROWS;
    const int tid  = threadIdx.x;
    const int wv   = tid >> 6;            // 0..7
    const int lane = tid & 63;

    if (tid == 0) lcnt = 0;

    // ---- i-boxes for both rows (broadcast loads) ----
    float xi[ROWS], yi[ROWS], ri[ROWS];
    bool rowok[ROWS];
#pragma unroll
    for (int rl = 0; rl < ROWS; ++rl) {
        int i = i0 + rl;
        rowok[rl] = (i < m);
        int ic = rowok[rl] ? i : (m - 1);
        const float* b = boxes + (size_t)ic * 7;
        float dx = b[3], dy = b[4];
        xi[rl] = b[0]; yi[rl] = b[1];
        ri[rl] = 0.5f * sqrtf(dx * dx + dy * dy) + 0.005f;
    }

    const unsigned long long below = (1ull << lane) - 1ull;

    // ---- chunked stage + dual-row cull ----
    for (int c0 = 0; c0 < n; c0 += CHUNKB) {
        int cb = n - c0; if (cb > CHUNKB) cb = CHUNKB;
        int words = cb * 7;
        const float* src = boxes + (size_t)(m + c0) * 7;

        if ((((size_t)src) & 15) == 0) {
            int n4 = words >> 2;
            const float4* s4 = (const float4*)src;
            float4* d4 = (float4*)chunk;
            for (int t = tid; t < n4; t += 512) d4[t] = s4[t];
            for (int t = (n4 << 2) + tid; t < words; t += 512)
                chunk[t] = src[t];
        } else {
            for (int t = tid; t < words; t += 512) chunk[t] = src[t];
        }
        __syncthreads();   // chunk ready (1st iter also publishes lcnt=0)

        // cull: one box per thread-iter, tested against BOTH rows
        for (int tt = tid; tt < cb; tt += 512) {
            int j = c0 + tt;
            const float* bj = &chunk[tt * 7];      // stride-7: 2-way, free
            float xj = bj[0], yj = bj[1];
            float dxj = bj[3], dyj = bj[4];
            float rj = 0.5f * sqrtf(dxj * dxj + dyj * dyj) + 0.005f;

#pragma unroll
            for (int rl = 0; rl < ROWS; ++rl) {
                bool keep = false;
                if (rowok[rl]) {
                    float ddx = xi[rl] - xj, ddy = yi[rl] - yj;
                    float rr = ri[rl] + rj;
                    keep = (ddx * ddx + ddy * ddy) <= rr * rr;
                    if (!keep) out[(size_t)(i0 + rl) * n + j] = 0.0f;
                }
                unsigned long long mask = __ballot(keep);
                int c = __popcll(mask);
                if (c > 0) {
                    int lead = __ffsll(mask) - 1;
                    unsigned base = 0;
                    if (lane == lead) base = atomicAdd(&lcnt, (unsigned)c);
                    base = (unsigned)__shfl((int)base, lead, 64);
                    if (keep) {
                        int rank = __popcll(mask & below);
                        wl[base + rank] =
                            (unsigned short)(((unsigned)rl << 12) | (unsigned)j);
                    }
                }
            }
        }
        __syncthreads();   // chunk consumed; safe to overwrite next iter
    }

    // ---- phase 2: packed survivors; round r handled by wave (i0/2 + r)&7 ----
    unsigned cnt = lcnt;
    unsigned r = 0;
    for (unsigned base = 0; base < cnt; base += 64, ++r) {
        if ((int)(((unsigned)blockIdx.x + r) & 7u) == wv) {
            unsigned t = base + (unsigned)lane;
            if (t < cnt) {
                unsigned e = wl[t];
                int rl = (int)(e >> 12);
                int j  = (int)(e & 0xFFFu);
                int i  = i0 + rl;
                out[(size_t)i * n + j] =
                    pair_area(boxes + (size_t)i * 7,
                              boxes + (size_t)(m + j) * 7);
            }
        }
    }
}

// ============================================================================
// Fallback pipeline — unchanged (only for odd shapes).
// ============================================================================
__global__ __launch_bounds__(256) void prep_kernel(
    const float* __restrict__ boxes, float* __restrict__ xs,
    float* __restrict__ ys, float* __restrict__ rs,
    unsigned* __restrict__ counters, int total)
{
    int t = blockIdx.x * blockDim.x + threadIdx.x;
    if (t < NREG * CTR_STRIDE) counters[t] = 0;
    if (t < total) {
        float dx = boxes[(size_t)t * 7 + 3];
        float dy = boxes[(size_t)t * 7 + 4];
        xs[t] = boxes[(size_t)t * 7 + 0];
        ys[t] = boxes[(size_t)t * 7 + 1];
        rs[t] = 0.5f * sqrtf(dx * dx + dy * dy) + 0.005f;
    }
}

__global__ __launch_bounds__(256) void cull_kernel(
    const float* __restrict__ xs, const float* __restrict__ ys,
    const float* __restrict__ rs, float* __restrict__ out,
    unsigned* __restrict__ counters, unsigned* __restrict__ regions,
    int m, int n, unsigned reg_cap)
{
    int jb = blockIdx.x, i = blockIdx.y;
    int tid = threadIdx.x;
    int j = jb * 256 + tid;

    bool keep = false;
    if (j < n) {
        float dx = xs[i] - xs[m + j];
        float dy = ys[i] - ys[m + j];
        float rr = rs[i] + rs[m + j];
        keep = (dx * dx + dy * dy) <= rr * rr;
        out[(size_t)i * n + j] = 0.0f;
    }

    unsigned long long mask = __ballot(keep);
    if (mask == 0ull) return;

    int lane = tid & 63;
    unsigned gwid = ((unsigned)(i * gridDim.x + jb) << 2) | ((unsigned)tid >> 6);
    unsigned region = gwid & (NREG - 1);

    int c = __popcll(mask);
    int lead = __ffsll((unsigned long long)mask) - 1;
    unsigned pos = 0;
    if (lane == lead) pos = atomicAdd(&counters[region * CTR_STRIDE], (unsigned)c);
    pos = (unsigned)__shfl((int)pos, lead, 64);
    if (keep) {
        int rank = __popcll(mask & ((1ull << lane) - 1ull));
        regions[(size_t)region * reg_cap + pos + rank] =
            ((unsigned)i << 12) | (unsigned)j;
    }
}

__global__ __launch_bounds__(64) void process_kernel(
    const float* __restrict__ boxes, float* __restrict__ out,
    const unsigned* __restrict__ counters, const unsigned* __restrict__ regions,
    int m, int n, unsigned reg_cap)
{
    unsigned region = blockIdx.x >> 2;
    unsigned cnt = counters[region * CTR_STRIDE];
    const unsigned* seg = regions + (size_t)region * reg_cap;
    for (unsigned t = ((blockIdx.x & 3u) << 6) | threadIdx.x; t < cnt; t += 256) {
        unsigned v = seg[t];
        int i = (int)(v >> 12);
        int j = (int)(v & 4095u);
        const float* A = boxes + (size_t)i * 7;
        const float* B = boxes + (size_t)(m + j) * 7;
        out[(size_t)i * n + j] = pair_area(A, B);
    }
}

__global__ __launch_bounds__(256) void overlap_kernel(
    const float* __restrict__ boxes, float* __restrict__ out, int m, int n)
{
    int j = blockIdx.x * blockDim.x + threadIdx.x;
    int i = blockIdx.y;
    if (j >= n) return;
    const float* A = boxes + (size_t)i * 7;
    const float* B = boxes + (size_t)(m + j) * 7;
    out[(size_t)i * n + j] = pair_area(A, B);
}

extern "C" void kernel_launch(void* const* d_in, const int* in_sizes, int n_in,
                              void* d_out, int out_size, void* d_ws, size_t ws_size,
                              hipStream_t stream) {
    const float* boxes = (const float*)d_in[0];
    float* out = (float*)d_out;
    int total = in_sizes[0] / 7;   // 3000 boxes
    int m = total / 3;             // 1000
    int n = total - m;             // 2000

    // ---------------- single-dispatch row-pair kernel ----------------
    if (n > 0 && n <= MAXN_LDS && m >= 1) {
        int nb = (m + ROWS - 1) / ROWS;
        hipLaunchKernelGGL(rowpair_kernel, dim3((unsigned)nb), dim3(512),
                           0, stream, boxes, out, m, n);
        return;
    }

    // ---------------- fallback: verified 3-kernel pipeline ----------------
    int bpr = (n + 255) / 256;
    unsigned total_waves = (unsigned)(bpr * m) * 4u;
    unsigned reg_cap = ((total_waves + NREG - 1) / NREG) * 64u;

    size_t ctr_off = 0;
    size_t xs_off  = ctr_off + (size_t)NREG * CTR_STRIDE * 4;
    size_t ys_off  = xs_off + (size_t)total * 4;
    size_t rs_off  = ys_off + (size_t)total * 4;
    size_t reg_off = ((rs_off + (size_t)total * 4) + 255) & ~(size_t)255;
    size_t need    = reg_off + (size_t)NREG * reg_cap * 4;

    if (ws_size < need || n > 4095) {
        dim3 block(256, 1, 1);
        dim3 grid((n + 255) / 256, m, 1);
        hipLaunchKernelGGL(overlap_kernel, grid, block, 0, stream, boxes, out, m, n);
        return;
    }

    unsigned* counters = (unsigned*)((char*)d_ws + ctr_off);
    float* xs = (float*)((char*)d_ws + xs_off);
    float* ys = (float*)((char*)d_ws + ys_off);
    float* rs = (float*)((char*)d_ws + rs_off);
    unsigned* regions = (unsigned*)((char*)d_ws + reg_off);

    int prep_threads = (NREG * CTR_STRIDE > total) ? NREG * CTR_STRIDE : total;
    hipLaunchKernelGGL(prep_kernel, dim3((prep_threads + 255) / 256), dim3(256),
                       0, stream, boxes, xs, ys, rs, counters, total);

    hipLaunchKernelGGL(cull_kernel, dim3(bpr, m, 1), dim3(256), 0, stream,
                       xs, ys, rs, out, counters, regions, m, n, reg_cap);

    hipLaunchKernelGGL(process_kernel, dim3(NREG * 4, 1, 1), dim3(64), 0, stream,
                       boxes, out, counters, regions, m, n, reg_cap);
}